// Round 8
// baseline (111.922 us; speedup 1.0000x reference)
//
#include <hip/hip_runtime.h>

#define THREADS 512

// raw barrier: wait LDS ops only (NOT vmcnt) so global loads/stores stay in
// flight across the barrier. "memory" clobber pins C++ LDS access order.
#define BAR() do { asm volatile("s_waitcnt lgkmcnt(0)" ::: "memory"); \
                   __builtin_amdgcn_s_barrier();                      \
                   asm volatile("" ::: "memory"); } while (0)

// read one real sample j (0..1023) of frame-slot F from split re/im slots
#define SLOTRD(F, j) s_slot[((j) & 1)*4176 + (F)*522 + ((j) >> 1)]

// -------- radix-8 inverse DFT over register index: u[n] = sum_k v[k] e^{+2*pi*i*n*k/8}
__device__ __forceinline__ void dft8(float* vr, float* vi) {
    float t0r=vr[0]+vr[4], t0i=vi[0]+vi[4];
    float t1r=vr[0]-vr[4], t1i=vi[0]-vi[4];
    float t2r=vr[2]+vr[6], t2i=vi[2]+vi[6];
    float t3r=vr[2]-vr[6], t3i=vi[2]-vi[6];
    float t4r=vr[1]+vr[5], t4i=vi[1]+vi[5];
    float t5r=vr[1]-vr[5], t5i=vi[1]-vi[5];
    float t6r=vr[3]+vr[7], t6i=vi[3]+vi[7];
    float t7r=vr[3]-vr[7], t7i=vi[3]-vi[7];
    float e0r=t0r+t2r, e0i=t0i+t2i;
    float e1r=t1r-t3i, e1i=t1i+t3r;   // t1 + i*t3
    float e2r=t0r-t2r, e2i=t0i-t2i;
    float e3r=t1r+t3i, e3i=t1i-t3r;   // t1 - i*t3
    float o0r=t4r+t6r, o0i=t4i+t6i;
    float o1r=t5r-t7i, o1i=t5i+t7r;
    float o2r=t4r-t6r, o2i=t4i-t6i;
    float o3r=t5r+t7i, o3i=t5i-t7r;
    const float C = 0.70710678118654752f;
    float w1r = C*(o1r - o1i), w1i = C*(o1r + o1i);   // W8^1 * o1
    float w2r = -o2i,          w2i = o2r;             // i * o2
    float w3r = -C*(o3r + o3i), w3i = C*(o3r - o3i);  // W8^3 * o3
    vr[0]=e0r+o0r; vi[0]=e0i+o0i;
    vr[1]=e1r+w1r; vi[1]=e1i+w1i;
    vr[2]=e2r+w2r; vi[2]=e2i+w2i;
    vr[3]=e3r+w3r; vi[3]=e3i+w3i;
    vr[4]=e0r-o0r; vi[4]=e0i-o0i;
    vr[5]=e1r-w1r; vi[5]=e1i-w1i;
    vr[6]=e2r-w2r; vi[6]=e2i-w2i;
    vr[7]=e3r-w3r; vi[7]=e3i-w3i;
}

// packed irfft-1024 as 512-pt complex IFFT, in-place in split re/im slot
__device__ __forceinline__ void fft512(float* Re, float* Im, int l,
                                       const float2* s_twzb, const float2* s_tw64,
                                       const float2* s_tw512) {
    const int a_ = l >> 3, b_ = l & 7;
    float zr[8], zi[8];
    float cw = s_twzb[l].x, sw_ = s_twzb[l].y;
    const float C8 = 0.92387953251128675f, S8 = 0.38268343236508977f; // e^{i*pi/8}
    #pragma unroll
    for (int k0 = 0; k0 < 8; ++k0) {
        int k = (k0<<6) + l;
        float xkr = Re[k],     xki = Im[k];
        float xmr = Re[512-k], xmi = Im[512-k];
        if (k == 0) { xki = 0.f; xmi = 0.f; }   // zero Im(X0), Im(X512)
        float Er = 0.5f*(xkr + xmr), Ei = 0.5f*(xki - xmi);
        float Dr = 0.5f*(xkr - xmr), Di = 0.5f*(xki + xmi);
        float Or = cw*Dr - sw_*Di,  Oi = sw_*Dr + cw*Di;
        zr[k0] = Er - Oi;
        zi[k0] = Ei + Or;
        float nc = cw*C8 - sw_*S8; sw_ = sw_*C8 + cw*S8; cw = nc;
    }
    dft8(zr, zi);
    // exchange 1 (XOR-swizzled, <=2-way)
    #pragma unroll
    for (int q = 0; q < 8; ++q) {
        int idx = (q<<6) + l;
        Re[idx ^ (((idx>>6)&7)<<3)] = zr[q];
        Im[idx ^ (((idx>>6)&7)<<3)] = zi[q];
    }
    #pragma unroll
    for (int q = 0; q < 8; ++q) {
        int idx = (a_<<6) + (q<<3) + b_;
        int ph = idx ^ (((idx>>6)&7)<<3);
        zr[q] = Re[ph]; zi[q] = Im[ph];
    }
    { // twiddle2: w64^{n0*k1}, incremental
        float c1 = s_tw64[a_].x, s1 = s_tw64[a_].y;
        float cr = c1, ci = s1;
        #pragma unroll
        for (int q = 1; q < 8; ++q) {
            float tr = zr[q]*cr - zi[q]*ci;
            zi[q] = zr[q]*ci + zi[q]*cr;
            zr[q] = tr;
            float nc = cr*c1 - ci*s1; ci = ci*c1 + cr*s1; cr = nc;
        }
    }
    dft8(zr, zi);
    // exchange 2
    #pragma unroll
    for (int q = 0; q < 8; ++q) {
        int idx = (b_<<6) + (q<<3) + a_;
        int ph = idx ^ (((idx>>6)&7)<<3);
        Re[ph] = zr[q]; Im[ph] = zi[q];
    }
    #pragma unroll
    for (int q = 0; q < 8; ++q) {
        int idx = (q<<6) + l;
        int ph = idx ^ (((idx>>6)&7)<<3);
        zr[q] = Re[ph]; zi[q] = Im[ph];
    }
    { // twiddle3: w512^{(n1*8+n0)*k2}, incremental
        float c1 = s_tw512[l].x, s1 = s_tw512[l].y;
        float cr = c1, ci = s1;
        #pragma unroll
        for (int q = 1; q < 8; ++q) {
            float tr = zr[q]*cr - zi[q]*ci;
            zi[q] = zr[q]*ci + zi[q]*cr;
            zr[q] = tr;
            float nc = cr*c1 - ci*s1; ci = ci*c1 + cr*s1; cr = nc;
        }
    }
    dft8(zr, zi);
    // output: lane l, reg q holds z[64q + l]; x[2n]=Re z[n], x[2n+1]=Im z[n]
    #pragma unroll
    for (int q = 0; q < 8; ++q) {
        Re[(q<<6) + l] = zr[q];
        Im[(q<<6) + l] = zi[q];
    }
}

// one block = (batch b, 16 frames): two 8-frame FFT rounds sharing LDS slots.
// Reads full 64B cache lines per spectrum row -> no HBM over-fetch.
template<bool USE_WS>
__global__ __launch_bounds__(512, 6) void istft_main(const float* __restrict__ spec_re,
                                                     const float* __restrict__ spec_im,
                                                     const float* __restrict__ mask,
                                                     float* __restrict__ out,
                                                     float* __restrict__ wsL,
                                                     float* __restrict__ wsR)
{
    const int G   = blockIdx.x;   // frame-group 0..127 (frames [16G, 16G+16))
    const int b   = blockIdx.y;   // batch 0..15
    const int tid = threadIdx.x;

    __shared__ float  s_slot[8352];   // 8 slots x 522: re [0,4176), im [4176,8352)
    __shared__ float  s_wt[1024];     // hann(j)/512
    __shared__ float  s_envr[256];    // 1 / (periodic fold of hann^2)
    __shared__ float  s_maskx[22];    // mask frames 16G-3 .. 16G+18 (OOR = 0)
    __shared__ float  s_ps[23];       // prefix sums of s_maskx
    __shared__ float2 s_twzb[64];     // e^{i*pi*l/512}
    __shared__ float2 s_tw64[8];      // e^{2*pi*i*a/64}
    __shared__ float2 s_tw512[64];    // e^{2*pi*i*l/512}

    // ---- issue round-1 global loads FIRST (latency hides under table build) ----
    const size_t base = (size_t)b * 513 * 2048 + (size_t)(G * 16);
    const int n0 = tid >> 1, q4 = (tid & 1) * 4;   // chunk c=tid: row n0, frames q4..q4+3
    const int n1 = n0 + 256;                        // chunk c=tid+512 (same q4)
    float4 ar0, ai0, ar1, ai1, ar2, ai2;
    float4 mk1, mk2;
    float mxv = 0.f;
    {
        size_t off0 = base + (size_t)n0 * 2048 + (size_t)q4;
        ar0 = *(const float4*)(spec_re + off0);
        ai0 = *(const float4*)(spec_im + off0);
        size_t off1 = base + (size_t)n1 * 2048 + (size_t)q4;
        ar1 = *(const float4*)(spec_re + off1);
        ai1 = *(const float4*)(spec_im + off1);
        if (tid < 2) {   // Nyquist row 512, quarter q=tid
            size_t off2 = base + (size_t)512 * 2048 + (size_t)(tid * 4);
            ar2 = *(const float4*)(spec_re + off2);
            ai2 = *(const float4*)(spec_im + off2);
        }
        mk1 = *(const float4*)(mask + b*2048 + G*16 + q4);
        if (tid < 22) {
            int gf = G*16 - 3 + tid;
            mxv = (gf >= 0 && gf < 2048) ? mask[b*2048 + gf] : 0.f;
        }
    }

    // ---- tables (hardware trig; accuracy ~1e-5 << 2e-2 threshold) ----
    for (int i = tid; i < 1024; i += THREADS) {
        float w = 0.5f - 0.5f * __cosf(6.2831853071795864f * (float)i * (1.0f/1024.0f));
        s_wt[i] = w * (1.0f/512.0f);
    }
    if (tid < 256) {
        float e = 0.f;
        #pragma unroll
        for (int k = 0; k < 4; ++k) {
            float w = 0.5f - 0.5f * __cosf(6.2831853071795864f * (float)(tid + (k<<8)) * (1.0f/1024.0f));
            e += w * w;
        }
        s_envr[tid] = 1.0f / e;
    }
    if (tid < 64) {
        float s1, c1, s2, c2;
        __sincosf(3.1415926535897932f * (float)tid * (1.0f/512.0f), &s1, &c1);
        s_twzb[tid] = make_float2(c1, s1);
        __sincosf(6.2831853071795864f * (float)tid * (1.0f/512.0f), &s2, &c2);
        s_tw512[tid] = make_float2(c2, s2);
    }
    if (tid < 8) {
        float s3, c3;
        __sincosf(6.2831853071795864f * (float)tid * (1.0f/64.0f), &s3, &c3);
        s_tw64[tid] = make_float2(c3, s3);
    }
    if (tid < 22) s_maskx[tid] = mxv;

    // ---- stage round 1 (frames 0..7), mask folded ----
    {
        const float* mp = (const float*)&mk1;
        #pragma unroll
        for (int f = 0; f < 4; ++f) {
            s_slot[       (q4+f)*522 + n0] = ((const float*)&ar0)[f] * mp[f];
            s_slot[4176 + (q4+f)*522 + n0] = ((const float*)&ai0)[f] * mp[f];
            s_slot[       (q4+f)*522 + n1] = ((const float*)&ar1)[f] * mp[f];
            s_slot[4176 + (q4+f)*522 + n1] = ((const float*)&ai1)[f] * mp[f];
        }
        if (tid < 2) {
            #pragma unroll
            for (int f = 0; f < 4; ++f) {
                s_slot[       (tid*4+f)*522 + 512] = ((const float*)&ar2)[f] * mp[f];
                s_slot[4176 + (tid*4+f)*522 + 512] = ((const float*)&ai2)[f] * mp[f];
            }
        }
    }
    // ---- issue round-2 loads (frames 8..15); hide under FFT1 + gather1 ----
    float4 br0, bi0, br1, bi1, br2, bi2;
    {
        size_t off0 = base + (size_t)n0 * 2048 + (size_t)(q4 + 8);
        br0 = *(const float4*)(spec_re + off0);
        bi0 = *(const float4*)(spec_im + off0);
        size_t off1 = base + (size_t)n1 * 2048 + (size_t)(q4 + 8);
        br1 = *(const float4*)(spec_re + off1);
        bi1 = *(const float4*)(spec_im + off1);
        if (tid < 2) {
            size_t off2 = base + (size_t)512 * 2048 + (size_t)(tid * 4 + 8);
            br2 = *(const float4*)(spec_re + off2);
            bi2 = *(const float4*)(spec_im + off2);
        }
        mk2 = *(const float4*)(mask + b*2048 + G*16 + 8 + q4);
    }
    if (tid == 0) {
        float acc = 0.f;
        s_ps[0] = 0.f;
        #pragma unroll
        for (int i = 0; i < 22; ++i) { acc += s_maskx[i]; s_ps[i+1] = acc; }
    }
    BAR();   // staging + tables visible

    // ---- FFT round 1: wave wv handles frame wv ----
    __builtin_amdgcn_s_setprio(1);
    {
        const int wv = tid >> 6, l = tid & 63;
        fft512(&s_slot[wv*522], &s_slot[4176 + wv*522], l, s_twzb, s_tw64, s_tw512);
    }
    __builtin_amdgcn_s_setprio(0);
    BAR();   // FFT1 results visible

    const int P0 = G << 12;   // 4096*G
    float* yout = out + (size_t)b * 524288;
    float* mout = out + 16ull*524288 + (size_t)b * 524288;

    // ---- gather round 1 ----
    // left strip p in [0,768)
    #pragma unroll
    for (int v = 0; v < 2; ++v) {
        int p = (v << 9) + tid;
        if (v == 0 || tid < 256) {
            int thi = p >> 8;                 // 0..2
            float acc = 0.f;
            for (int F = 0; F <= thi; ++F) {
                int j = p - (F << 8);
                acc += SLOTRD(F, j) * s_wt[j];
            }
            float fm = s_ps[thi + 4] - s_ps[((p - 768) >> 8) + 3];
            if (G == 0) {
                if (p >= 384) {
                    float e = 0.f;
                    for (int t = 0; t <= thi; ++t) {
                        float w = s_wt[p - (t << 8)] * 512.0f;
                        e += w * w;
                    }
                    yout[p - 384] = acc / e;
                    mout[p - 384] = (fm > 0.f) ? 1.0f : 0.0f;
                }
            } else {
                int s = P0 + p - 384;
                if (USE_WS) wsL[(size_t)(((b << 7) + G)) * 768 + p] = acc;
                else        atomicAdd(&yout[s], acc);
                mout[s] = (fm > 0.f) ? 1.0f : 0.0f;
            }
        }
    }
    // interior1 p in [768,2048): 4 terms
    #pragma unroll
    for (int q = 1; q < 4; ++q) {
        int p = (q << 9) + tid;
        if (q > 1 || tid >= 256) {
            int F0 = (p >> 8) - 3;
            float acc = 0.f;
            #pragma unroll
            for (int u = 0; u < 4; ++u) {
                int F = F0 + u;
                int j = p - (F << 8);
                acc += SLOTRD(F, j) * s_wt[j];
            }
            float fm = s_ps[(p >> 8) + 4] - s_ps[F0 + 3];
            int s = P0 + p - 384;
            yout[s] = acc * s_envr[p & 255];
            mout[s] = (fm > 0.f) ? 1.0f : 0.0f;
        }
    }
    // carry region p in [2048,2816): partial sums from frames <=7, kept in regs
    float carry0, carry1 = 0.f;
    {
        int p = 2048 + tid;
        int Flo = (1280 + tid) >> 8;          // 5 (tid<256) or 6
        float acc = 0.f;
        for (int F = Flo; F < 8; ++F) {
            int j = p - (F << 8);
            acc += SLOTRD(F, j) * s_wt[j];
        }
        carry0 = acc;
        if (tid < 256) {
            int j = 768 + tid;                 // p=2560+tid, F=7 only
            carry1 = SLOTRD(7, j) * s_wt[j];
        }
    }
    BAR();   // gather1 reads done -> slots free

    // ---- stage round 2 (frames 8..15 into slots 0..7) ----
    {
        const float* mp = (const float*)&mk2;
        #pragma unroll
        for (int f = 0; f < 4; ++f) {
            s_slot[       (q4+f)*522 + n0] = ((const float*)&br0)[f] * mp[f];
            s_slot[4176 + (q4+f)*522 + n0] = ((const float*)&bi0)[f] * mp[f];
            s_slot[       (q4+f)*522 + n1] = ((const float*)&br1)[f] * mp[f];
            s_slot[4176 + (q4+f)*522 + n1] = ((const float*)&bi1)[f] * mp[f];
        }
        if (tid < 2) {
            #pragma unroll
            for (int f = 0; f < 4; ++f) {
                s_slot[       (tid*4+f)*522 + 512] = ((const float*)&br2)[f] * mp[f];
                s_slot[4176 + (tid*4+f)*522 + 512] = ((const float*)&bi2)[f] * mp[f];
            }
        }
    }
    BAR();   // staging2 visible

    // ---- FFT round 2 ----
    __builtin_amdgcn_s_setprio(1);
    {
        const int wv = tid >> 6, l = tid & 63;
        fft512(&s_slot[wv*522], &s_slot[4176 + wv*522], l, s_twzb, s_tw64, s_tw512);
    }
    __builtin_amdgcn_s_setprio(0);
    BAR();   // FFT2 results visible

    // ---- gather round 2 (slot s holds frame 8+s) ----
    // carry retire p in [2048,2560)
    {
        int p = 2048 + tid;
        float acc = carry0;
        { int j = tid;       acc += SLOTRD(0, j) * s_wt[j]; }        // F=8
        if (tid >= 256) { int j = tid - 256; acc += SLOTRD(1, j) * s_wt[j]; }  // F=9
        float fm = s_ps[(p >> 8) + 4] - s_ps[((p - 768) >> 8) + 3];
        int s = P0 + p - 384;
        yout[s] = acc * s_envr[p & 255];
        mout[s] = (fm > 0.f) ? 1.0f : 0.0f;
    }
    if (tid < 256) {   // p in [2560,2816)
        int p = 2560 + tid;
        float acc = carry1;
        { int j = 512 + tid; acc += SLOTRD(0, j) * s_wt[j]; }        // F=8
        { int j = 256 + tid; acc += SLOTRD(1, j) * s_wt[j]; }        // F=9
        { int j = tid;       acc += SLOTRD(2, j) * s_wt[j]; }        // F=10
        float fm = s_ps[(p >> 8) + 4] - s_ps[((p - 768) >> 8) + 3];
        int s = P0 + p - 384;
        yout[s] = acc * s_envr[p & 255];
        mout[s] = (fm > 0.f) ? 1.0f : 0.0f;
    }
    // interior2 p in [2816,4096): 4 terms
    #pragma unroll
    for (int v = 0; v < 3; ++v) {
        int p = 2816 + (v << 9) + tid;
        if (v < 2 || tid < 256) {
            int F0 = (p >> 8) - 3;             // 8..12
            float acc = 0.f;
            #pragma unroll
            for (int u = 0; u < 4; ++u) {
                int F = F0 + u;
                int j = p - (F << 8);
                acc += SLOTRD(F - 8, j) * s_wt[j];
            }
            float fm = s_ps[(p >> 8) + 4] - s_ps[F0 + 3];
            int s = P0 + p - 384;
            yout[s] = acc * s_envr[p & 255];
            mout[s] = (fm > 0.f) ? 1.0f : 0.0f;
        }
    }
    // right strip p in [4096,4864)
    #pragma unroll
    for (int v = 0; v < 2; ++v) {
        int p = 4096 + (v << 9) + tid;
        if (v == 0 || tid < 256) {
            int Flo = (p - 768) >> 8;          // 13..15
            float acc = 0.f;
            for (int F = Flo; F < 16; ++F) {
                int j = p - (F << 8);
                acc += SLOTRD(F - 8, j) * s_wt[j];
            }
            float fm = s_ps[min(p >> 8, 18) + 4] - s_ps[Flo + 3];
            if (G == 127) {
                if (p < 4480) {
                    float e = 0.f;
                    for (int t = Flo; t < 16; ++t) {
                        float w = s_wt[p - (t << 8)] * 512.0f;
                        e += w * w;
                    }
                    int s = P0 + p - 384;
                    yout[s] = acc / e;
                    mout[s] = (fm > 0.f) ? 1.0f : 0.0f;
                }
            } else {
                int s = P0 + p - 384;
                if (USE_WS) wsR[(size_t)(((b << 7) + G)) * 768 + (p - 4096)] = acc;
                else        atomicAdd(&yout[s], acc);
                mout[s] = (fm > 0.f) ? 1.0f : 0.0f;
            }
        }
    }
}

// ws path: combine the two strip partials, divide by (periodic) env.
__global__ void istft_fixup_ws(const float* __restrict__ wsL, const float* __restrict__ wsR,
                               float* __restrict__ out) {
    int idx = blockIdx.x * 256 + threadIdx.x;
    if (idx >= 16*127*768) return;
    int q  = idx % 768;
    int t_ = idx / 768;
    int g  = (t_ % 127) + 1;
    int b  = t_ / 127;
    float a = wsR[(size_t)((b << 7) + (g-1)) * 768 + q]
            + wsL[(size_t)((b << 7) + g) * 768 + q];
    int j0 = q & 255;
    float e = 0.f;
    #pragma unroll
    for (int u = 0; u < 4; ++u) {
        float w = 0.5f - 0.5f * __cosf(6.2831853071795864f * (float)(j0 + (u<<8)) * (1.0f/1024.0f));
        e += w * w;
    }
    out[(size_t)b*524288 + (size_t)((g << 12) + q - 384)] = a / e;
}

// atomic-fallback path
__global__ void istft_zero(float* __restrict__ out) {
    int idx = blockIdx.x * 256 + threadIdx.x;
    if (idx >= 16*127*768) return;
    int q  = idx % 768;
    int t_ = idx / 768;
    int g  = (t_ % 127) + 1;
    int b  = t_ / 127;
    out[(size_t)b*524288 + (g << 12) + q - 384] = 0.f;
}

__global__ void istft_fixup_at(float* __restrict__ out) {
    int idx = blockIdx.x * 256 + threadIdx.x;
    if (idx >= 16*127*768) return;
    int q  = idx % 768;
    int t_ = idx / 768;
    int g  = (t_ % 127) + 1;
    int b  = t_ / 127;
    int j0 = q & 255;
    float e = 0.f;
    #pragma unroll
    for (int u = 0; u < 4; ++u) {
        float w = 0.5f - 0.5f * __cosf(6.2831853071795864f * (float)(j0 + (u<<8)) * (1.0f/1024.0f));
        e += w * w;
    }
    size_t o = (size_t)b*524288 + (size_t)((g << 12) + q - 384);
    out[o] = out[o] / e;
}

extern "C" void kernel_launch(void* const* d_in, const int* in_sizes, int n_in,
                              void* d_out, int out_size, void* d_ws, size_t ws_size,
                              hipStream_t stream) {
    (void)in_sizes; (void)n_in; (void)out_size;
    const float* spec_re = (const float*)d_in[0];
    const float* spec_im = (const float*)d_in[1];
    const float* mask    = (const float*)d_in[2];
    float* out = (float*)d_out;
    const int nstrip = 16*127*768;
    const size_t ws_need = 2ull * 16 * 128 * 768 * 4;   // 12.6 MB
    if (ws_size >= ws_need && d_ws != nullptr) {
        float* wsL = (float*)d_ws;
        float* wsR = wsL + 16ull*128*768;
        istft_main<true><<<dim3(128, 16), 512, 0, stream>>>(spec_re, spec_im, mask, out, wsL, wsR);
        istft_fixup_ws<<<(nstrip + 255)/256, 256, 0, stream>>>(wsL, wsR, out);
    } else {
        istft_zero<<<(nstrip + 255)/256, 256, 0, stream>>>(out);
        istft_main<false><<<dim3(128, 16), 512, 0, stream>>>(spec_re, spec_im, mask, out, nullptr, nullptr);
        istft_fixup_at<<<(nstrip + 255)/256, 256, 0, stream>>>(out);
    }
}

// Round 9
// 109.184 us; speedup vs baseline: 1.0251x; 1.0251x over previous
//
#include <hip/hip_runtime.h>

#define THREADS 512

// raw barrier: wait LDS ops only (NOT vmcnt) so global loads/stores stay in
// flight across the barrier. "memory" clobber pins C++ LDS access order.
#define BAR() do { asm volatile("s_waitcnt lgkmcnt(0)" ::: "memory"); \
                   __builtin_amdgcn_s_barrier();                      \
                   asm volatile("" ::: "memory"); } while (0)

// read one real sample j (0..1023) of frame-slot F from split re/im slots
#define SLOTRD(F, j) s_slot[((j) & 1)*4176 + (F)*522 + ((j) >> 1)]

// -------- radix-8 inverse DFT over register index: u[n] = sum_k v[k] e^{+2*pi*i*n*k/8}
__device__ __forceinline__ void dft8(float* vr, float* vi) {
    float t0r=vr[0]+vr[4], t0i=vi[0]+vi[4];
    float t1r=vr[0]-vr[4], t1i=vi[0]-vi[4];
    float t2r=vr[2]+vr[6], t2i=vi[2]+vi[6];
    float t3r=vr[2]-vr[6], t3i=vi[2]-vi[6];
    float t4r=vr[1]+vr[5], t4i=vi[1]+vi[5];
    float t5r=vr[1]-vr[5], t5i=vi[1]-vi[5];
    float t6r=vr[3]+vr[7], t6i=vi[3]+vi[7];
    float t7r=vr[3]-vr[7], t7i=vi[3]-vi[7];
    float e0r=t0r+t2r, e0i=t0i+t2i;
    float e1r=t1r-t3i, e1i=t1i+t3r;   // t1 + i*t3
    float e2r=t0r-t2r, e2i=t0i-t2i;
    float e3r=t1r+t3i, e3i=t1i-t3r;   // t1 - i*t3
    float o0r=t4r+t6r, o0i=t4i+t6i;
    float o1r=t5r-t7i, o1i=t5i+t7r;
    float o2r=t4r-t6r, o2i=t4i-t6i;
    float o3r=t5r+t7i, o3i=t5i-t7r;
    const float C = 0.70710678118654752f;
    float w1r = C*(o1r - o1i), w1i = C*(o1r + o1i);   // W8^1 * o1
    float w2r = -o2i,          w2i = o2r;             // i * o2
    float w3r = -C*(o3r + o3i), w3i = C*(o3r - o3i);  // W8^3 * o3
    vr[0]=e0r+o0r; vi[0]=e0i+o0i;
    vr[1]=e1r+w1r; vi[1]=e1i+w1i;
    vr[2]=e2r+w2r; vi[2]=e2i+w2i;
    vr[3]=e3r+w3r; vi[3]=e3i+w3i;
    vr[4]=e0r-o0r; vi[4]=e0i-o0i;
    vr[5]=e1r-w1r; vi[5]=e1i-w1i;
    vr[6]=e2r-w2r; vi[6]=e2i-w2i;
    vr[7]=e3r-w3r; vi[7]=e3i-w3i;
}

// packed irfft-1024 as 512-pt complex IFFT, in-place in split re/im slot
__device__ __forceinline__ void fft512(float* Re, float* Im, int l,
                                       const float2* s_twzb, const float2* s_tw64,
                                       const float2* s_tw512) {
    const int a_ = l >> 3, b_ = l & 7;
    float zr[8], zi[8];
    float cw = s_twzb[l].x, sw_ = s_twzb[l].y;
    const float C8 = 0.92387953251128675f, S8 = 0.38268343236508977f; // e^{i*pi/8}
    #pragma unroll
    for (int k0 = 0; k0 < 8; ++k0) {
        int k = (k0<<6) + l;
        float xkr = Re[k],     xki = Im[k];
        float xmr = Re[512-k], xmi = Im[512-k];
        if (k == 0) { xki = 0.f; xmi = 0.f; }   // zero Im(X0), Im(X512)
        float Er = 0.5f*(xkr + xmr), Ei = 0.5f*(xki - xmi);
        float Dr = 0.5f*(xkr - xmr), Di = 0.5f*(xki + xmi);
        float Or = cw*Dr - sw_*Di,  Oi = sw_*Dr + cw*Di;
        zr[k0] = Er - Oi;
        zi[k0] = Ei + Or;
        float nc = cw*C8 - sw_*S8; sw_ = sw_*C8 + cw*S8; cw = nc;
    }
    dft8(zr, zi);
    // exchange 1 (XOR-swizzled, <=2-way)
    #pragma unroll
    for (int q = 0; q < 8; ++q) {
        int idx = (q<<6) + l;
        Re[idx ^ (((idx>>6)&7)<<3)] = zr[q];
        Im[idx ^ (((idx>>6)&7)<<3)] = zi[q];
    }
    #pragma unroll
    for (int q = 0; q < 8; ++q) {
        int idx = (a_<<6) + (q<<3) + b_;
        int ph = idx ^ (((idx>>6)&7)<<3);
        zr[q] = Re[ph]; zi[q] = Im[ph];
    }
    { // twiddle2: w64^{n0*k1}, incremental
        float c1 = s_tw64[a_].x, s1 = s_tw64[a_].y;
        float cr = c1, ci = s1;
        #pragma unroll
        for (int q = 1; q < 8; ++q) {
            float tr = zr[q]*cr - zi[q]*ci;
            zi[q] = zr[q]*ci + zi[q]*cr;
            zr[q] = tr;
            float nc = cr*c1 - ci*s1; ci = ci*c1 + cr*s1; cr = nc;
        }
    }
    dft8(zr, zi);
    // exchange 2
    #pragma unroll
    for (int q = 0; q < 8; ++q) {
        int idx = (b_<<6) + (q<<3) + a_;
        int ph = idx ^ (((idx>>6)&7)<<3);
        Re[ph] = zr[q]; Im[ph] = zi[q];
    }
    #pragma unroll
    for (int q = 0; q < 8; ++q) {
        int idx = (q<<6) + l;
        int ph = idx ^ (((idx>>6)&7)<<3);
        zr[q] = Re[ph]; zi[q] = Im[ph];
    }
    { // twiddle3: w512^{(n1*8+n0)*k2}, incremental
        float c1 = s_tw512[l].x, s1 = s_tw512[l].y;
        float cr = c1, ci = s1;
        #pragma unroll
        for (int q = 1; q < 8; ++q) {
            float tr = zr[q]*cr - zi[q]*ci;
            zi[q] = zr[q]*ci + zi[q]*cr;
            zr[q] = tr;
            float nc = cr*c1 - ci*s1; ci = ci*c1 + cr*s1; cr = nc;
        }
    }
    dft8(zr, zi);
    // output: lane l, reg q holds z[64q + l]; x[2n]=Re z[n], x[2n+1]=Im z[n]
    #pragma unroll
    for (int q = 0; q < 8; ++q) {
        Re[(q<<6) + l] = zr[q];
        Im[(q<<6) + l] = zi[q];
    }
}

// one block = (batch b, 16 frames): two 8-frame FFT rounds sharing LDS slots.
// Reads full 64B cache lines per spectrum row -> no HBM over-fetch.
// Round-2 loads are issued AFTER FFT1 (not before) so their live range never
// overlaps the FFT register peak -> no scratch spill (R8 lesson).
template<bool USE_WS>
__global__ __launch_bounds__(512, 6) void istft_main(const float* __restrict__ spec_re,
                                                     const float* __restrict__ spec_im,
                                                     const float* __restrict__ mask,
                                                     float* __restrict__ out,
                                                     float* __restrict__ wsL,
                                                     float* __restrict__ wsR)
{
    const int G   = blockIdx.x;   // frame-group 0..127 (frames [16G, 16G+16))
    const int b   = blockIdx.y;   // batch 0..15
    const int tid = threadIdx.x;

    __shared__ float  s_slot[8352];   // 8 slots x 522: re [0,4176), im [4176,8352)
    __shared__ float  s_wt[1024];     // hann(j)/512
    __shared__ float  s_envr[256];    // 1 / (periodic fold of hann^2)
    __shared__ float  s_maskx[22];    // mask frames 16G-3 .. 16G+18 (OOR = 0)
    __shared__ float  s_ps[23];       // prefix sums of s_maskx
    __shared__ float2 s_twzb[64];     // e^{i*pi*l/512}
    __shared__ float2 s_tw64[8];      // e^{2*pi*i*a/64}
    __shared__ float2 s_tw512[64];    // e^{2*pi*i*l/512}

    // ---- issue round-1 global loads FIRST (latency hides under table build) ----
    const size_t base = (size_t)b * 513 * 2048 + (size_t)(G * 16);
    const int n0 = tid >> 1, q4 = (tid & 1) * 4;   // chunk c=tid: row n0, frames q4..q4+3
    const int n1 = n0 + 256;                        // chunk c=tid+512 (same q4)
    float4 ar0, ai0, ar1, ai1, ar2, ai2;
    float4 mk1;
    float mxv = 0.f;
    {
        size_t off0 = base + (size_t)n0 * 2048 + (size_t)q4;
        ar0 = *(const float4*)(spec_re + off0);
        ai0 = *(const float4*)(spec_im + off0);
        size_t off1 = base + (size_t)n1 * 2048 + (size_t)q4;
        ar1 = *(const float4*)(spec_re + off1);
        ai1 = *(const float4*)(spec_im + off1);
        if (tid < 2) {   // Nyquist row 512, quarter q=tid
            size_t off2 = base + (size_t)512 * 2048 + (size_t)(tid * 4);
            ar2 = *(const float4*)(spec_re + off2);
            ai2 = *(const float4*)(spec_im + off2);
        }
        mk1 = *(const float4*)(mask + b*2048 + G*16 + q4);
        if (tid < 22) {
            int gf = G*16 - 3 + tid;
            mxv = (gf >= 0 && gf < 2048) ? mask[b*2048 + gf] : 0.f;
        }
    }

    // ---- tables (hardware trig; accuracy ~1e-5 << 2e-2 threshold) ----
    for (int i = tid; i < 1024; i += THREADS) {
        float w = 0.5f - 0.5f * __cosf(6.2831853071795864f * (float)i * (1.0f/1024.0f));
        s_wt[i] = w * (1.0f/512.0f);
    }
    if (tid < 256) {
        float e = 0.f;
        #pragma unroll
        for (int k = 0; k < 4; ++k) {
            float w = 0.5f - 0.5f * __cosf(6.2831853071795864f * (float)(tid + (k<<8)) * (1.0f/1024.0f));
            e += w * w;
        }
        s_envr[tid] = 1.0f / e;
    }
    if (tid < 64) {
        float s1, c1, s2, c2;
        __sincosf(3.1415926535897932f * (float)tid * (1.0f/512.0f), &s1, &c1);
        s_twzb[tid] = make_float2(c1, s1);
        __sincosf(6.2831853071795864f * (float)tid * (1.0f/512.0f), &s2, &c2);
        s_tw512[tid] = make_float2(c2, s2);
    }
    if (tid < 8) {
        float s3, c3;
        __sincosf(6.2831853071795864f * (float)tid * (1.0f/64.0f), &s3, &c3);
        s_tw64[tid] = make_float2(c3, s3);
    }
    if (tid < 22) s_maskx[tid] = mxv;

    // ---- stage round 1 (frames 0..7), mask folded ----
    {
        const float* mp = (const float*)&mk1;
        #pragma unroll
        for (int f = 0; f < 4; ++f) {
            s_slot[       (q4+f)*522 + n0] = ((const float*)&ar0)[f] * mp[f];
            s_slot[4176 + (q4+f)*522 + n0] = ((const float*)&ai0)[f] * mp[f];
            s_slot[       (q4+f)*522 + n1] = ((const float*)&ar1)[f] * mp[f];
            s_slot[4176 + (q4+f)*522 + n1] = ((const float*)&ai1)[f] * mp[f];
        }
        if (tid < 2) {
            #pragma unroll
            for (int f = 0; f < 4; ++f) {
                s_slot[       (tid*4+f)*522 + 512] = ((const float*)&ar2)[f] * mp[f];
                s_slot[4176 + (tid*4+f)*522 + 512] = ((const float*)&ai2)[f] * mp[f];
            }
        }
    }
    if (tid == 0) {
        float acc = 0.f;
        s_ps[0] = 0.f;
        #pragma unroll
        for (int i = 0; i < 22; ++i) { acc += s_maskx[i]; s_ps[i+1] = acc; }
    }
    BAR();   // staging + tables visible

    // ---- FFT round 1: wave wv handles frame wv ----
    __builtin_amdgcn_s_setprio(1);
    {
        const int wv = tid >> 6, l = tid & 63;
        fft512(&s_slot[wv*522], &s_slot[4176 + wv*522], l, s_twzb, s_tw64, s_tw512);
    }
    __builtin_amdgcn_s_setprio(0);
    BAR();   // FFT1 results visible

    // ---- issue round-2 loads NOW (hidden under gather1; short live range) ----
    float4 br0, bi0, br1, bi1, br2, bi2;
    float4 mk2;
    {
        size_t off0 = base + (size_t)n0 * 2048 + (size_t)(q4 + 8);
        br0 = *(const float4*)(spec_re + off0);
        bi0 = *(const float4*)(spec_im + off0);
        size_t off1 = base + (size_t)n1 * 2048 + (size_t)(q4 + 8);
        br1 = *(const float4*)(spec_re + off1);
        bi1 = *(const float4*)(spec_im + off1);
        if (tid < 2) {
            size_t off2 = base + (size_t)512 * 2048 + (size_t)(tid * 4 + 8);
            br2 = *(const float4*)(spec_re + off2);
            bi2 = *(const float4*)(spec_im + off2);
        }
        mk2 = *(const float4*)(mask + b*2048 + G*16 + 8 + q4);
    }

    const int P0 = G << 12;   // 4096*G
    float* yout = out + (size_t)b * 524288;
    float* mout = out + 16ull*524288 + (size_t)b * 524288;

    // ---- gather round 1 ----
    // left strip p in [0,768)
    #pragma unroll
    for (int v = 0; v < 2; ++v) {
        int p = (v << 9) + tid;
        if (v == 0 || tid < 256) {
            int thi = p >> 8;                 // 0..2
            float acc = 0.f;
            for (int F = 0; F <= thi; ++F) {
                int j = p - (F << 8);
                acc += SLOTRD(F, j) * s_wt[j];
            }
            float fm = s_ps[thi + 4] - s_ps[((p - 768) >> 8) + 3];
            if (G == 0) {
                if (p >= 384) {
                    float e = 0.f;
                    for (int t = 0; t <= thi; ++t) {
                        float w = s_wt[p - (t << 8)] * 512.0f;
                        e += w * w;
                    }
                    yout[p - 384] = acc / e;
                    mout[p - 384] = (fm > 0.f) ? 1.0f : 0.0f;
                }
            } else {
                int s = P0 + p - 384;
                if (USE_WS) wsL[(size_t)(((b << 7) + G)) * 768 + p] = acc;
                else        atomicAdd(&yout[s], acc);
                mout[s] = (fm > 0.f) ? 1.0f : 0.0f;
            }
        }
    }
    // interior1 p in [768,2048): 4 terms
    #pragma unroll
    for (int q = 1; q < 4; ++q) {
        int p = (q << 9) + tid;
        if (q > 1 || tid >= 256) {
            int F0 = (p >> 8) - 3;
            float acc = 0.f;
            #pragma unroll
            for (int u = 0; u < 4; ++u) {
                int F = F0 + u;
                int j = p - (F << 8);
                acc += SLOTRD(F, j) * s_wt[j];
            }
            float fm = s_ps[(p >> 8) + 4] - s_ps[F0 + 3];
            int s = P0 + p - 384;
            yout[s] = acc * s_envr[p & 255];
            mout[s] = (fm > 0.f) ? 1.0f : 0.0f;
        }
    }
    // carry region p in [2048,2816): partial sums from frames <=7, kept in regs
    float carry0, carry1 = 0.f;
    {
        int p = 2048 + tid;
        int Flo = (1280 + tid) >> 8;          // 5 (tid<256) or 6
        float acc = 0.f;
        for (int F = Flo; F < 8; ++F) {
            int j = p - (F << 8);
            acc += SLOTRD(F, j) * s_wt[j];
        }
        carry0 = acc;
        if (tid < 256) {
            int j = 768 + tid;                 // p=2560+tid, F=7 only
            carry1 = SLOTRD(7, j) * s_wt[j];
        }
    }
    BAR();   // gather1 reads done -> slots free

    // ---- stage round 2 (frames 8..15 into slots 0..7) ----
    {
        const float* mp = (const float*)&mk2;
        #pragma unroll
        for (int f = 0; f < 4; ++f) {
            s_slot[       (q4+f)*522 + n0] = ((const float*)&br0)[f] * mp[f];
            s_slot[4176 + (q4+f)*522 + n0] = ((const float*)&bi0)[f] * mp[f];
            s_slot[       (q4+f)*522 + n1] = ((const float*)&br1)[f] * mp[f];
            s_slot[4176 + (q4+f)*522 + n1] = ((const float*)&bi1)[f] * mp[f];
        }
        if (tid < 2) {
            #pragma unroll
            for (int f = 0; f < 4; ++f) {
                s_slot[       (tid*4+f)*522 + 512] = ((const float*)&br2)[f] * mp[f];
                s_slot[4176 + (tid*4+f)*522 + 512] = ((const float*)&bi2)[f] * mp[f];
            }
        }
    }
    BAR();   // staging2 visible

    // ---- FFT round 2 ----
    __builtin_amdgcn_s_setprio(1);
    {
        const int wv = tid >> 6, l = tid & 63;
        fft512(&s_slot[wv*522], &s_slot[4176 + wv*522], l, s_twzb, s_tw64, s_tw512);
    }
    __builtin_amdgcn_s_setprio(0);
    BAR();   // FFT2 results visible

    // ---- gather round 2 (slot s holds frame 8+s) ----
    // carry retire p in [2048,2560)
    {
        int p = 2048 + tid;
        float acc = carry0;
        { int j = tid;       acc += SLOTRD(0, j) * s_wt[j]; }        // F=8
        if (tid >= 256) { int j = tid - 256; acc += SLOTRD(1, j) * s_wt[j]; }  // F=9
        float fm = s_ps[(p >> 8) + 4] - s_ps[((p - 768) >> 8) + 3];
        int s = P0 + p - 384;
        yout[s] = acc * s_envr[p & 255];
        mout[s] = (fm > 0.f) ? 1.0f : 0.0f;
    }
    if (tid < 256) {   // p in [2560,2816)
        int p = 2560 + tid;
        float acc = carry1;
        { int j = 512 + tid; acc += SLOTRD(0, j) * s_wt[j]; }        // F=8
        { int j = 256 + tid; acc += SLOTRD(1, j) * s_wt[j]; }        // F=9
        { int j = tid;       acc += SLOTRD(2, j) * s_wt[j]; }        // F=10
        float fm = s_ps[(p >> 8) + 4] - s_ps[((p - 768) >> 8) + 3];
        int s = P0 + p - 384;
        yout[s] = acc * s_envr[p & 255];
        mout[s] = (fm > 0.f) ? 1.0f : 0.0f;
    }
    // interior2 p in [2816,4096): 4 terms
    #pragma unroll
    for (int v = 0; v < 3; ++v) {
        int p = 2816 + (v << 9) + tid;
        if (v < 2 || tid < 256) {
            int F0 = (p >> 8) - 3;             // 8..12
            float acc = 0.f;
            #pragma unroll
            for (int u = 0; u < 4; ++u) {
                int F = F0 + u;
                int j = p - (F << 8);
                acc += SLOTRD(F - 8, j) * s_wt[j];
            }
            float fm = s_ps[(p >> 8) + 4] - s_ps[F0 + 3];
            int s = P0 + p - 384;
            yout[s] = acc * s_envr[p & 255];
            mout[s] = (fm > 0.f) ? 1.0f : 0.0f;
        }
    }
    // right strip p in [4096,4864)
    #pragma unroll
    for (int v = 0; v < 2; ++v) {
        int p = 4096 + (v << 9) + tid;
        if (v == 0 || tid < 256) {
            int Flo = (p - 768) >> 8;          // 13..15
            float acc = 0.f;
            for (int F = Flo; F < 16; ++F) {
                int j = p - (F << 8);
                acc += SLOTRD(F - 8, j) * s_wt[j];
            }
            float fm = s_ps[min(p >> 8, 18) + 4] - s_ps[Flo + 3];
            if (G == 127) {
                if (p < 4480) {
                    float e = 0.f;
                    for (int t = Flo; t < 16; ++t) {
                        float w = s_wt[p - (t << 8)] * 512.0f;
                        e += w * w;
                    }
                    int s = P0 + p - 384;
                    yout[s] = acc / e;
                    mout[s] = (fm > 0.f) ? 1.0f : 0.0f;
                }
            } else {
                int s = P0 + p - 384;
                if (USE_WS) wsR[(size_t)(((b << 7) + G)) * 768 + (p - 4096)] = acc;
                else        atomicAdd(&yout[s], acc);
                mout[s] = (fm > 0.f) ? 1.0f : 0.0f;
            }
        }
    }
}

// ws path: combine the two strip partials, divide by (periodic) env.
__global__ void istft_fixup_ws(const float* __restrict__ wsL, const float* __restrict__ wsR,
                               float* __restrict__ out) {
    int idx = blockIdx.x * 256 + threadIdx.x;
    if (idx >= 16*127*768) return;
    int q  = idx % 768;
    int t_ = idx / 768;
    int g  = (t_ % 127) + 1;
    int b  = t_ / 127;
    float a = wsR[(size_t)((b << 7) + (g-1)) * 768 + q]
            + wsL[(size_t)((b << 7) + g) * 768 + q];
    int j0 = q & 255;
    float e = 0.f;
    #pragma unroll
    for (int u = 0; u < 4; ++u) {
        float w = 0.5f - 0.5f * __cosf(6.2831853071795864f * (float)(j0 + (u<<8)) * (1.0f/1024.0f));
        e += w * w;
    }
    out[(size_t)b*524288 + (size_t)((g << 12) + q - 384)] = a / e;
}

// atomic-fallback path
__global__ void istft_zero(float* __restrict__ out) {
    int idx = blockIdx.x * 256 + threadIdx.x;
    if (idx >= 16*127*768) return;
    int q  = idx % 768;
    int t_ = idx / 768;
    int g  = (t_ % 127) + 1;
    int b  = t_ / 127;
    out[(size_t)b*524288 + (g << 12) + q - 384] = 0.f;
}

__global__ void istft_fixup_at(float* __restrict__ out) {
    int idx = blockIdx.x * 256 + threadIdx.x;
    if (idx >= 16*127*768) return;
    int q  = idx % 768;
    int t_ = idx / 768;
    int g  = (t_ % 127) + 1;
    int b  = t_ / 127;
    int j0 = q & 255;
    float e = 0.f;
    #pragma unroll
    for (int u = 0; u < 4; ++u) {
        float w = 0.5f - 0.5f * __cosf(6.2831853071795864f * (float)(j0 + (u<<8)) * (1.0f/1024.0f));
        e += w * w;
    }
    size_t o = (size_t)b*524288 + (size_t)((g << 12) + q - 384);
    out[o] = out[o] / e;
}

extern "C" void kernel_launch(void* const* d_in, const int* in_sizes, int n_in,
                              void* d_out, int out_size, void* d_ws, size_t ws_size,
                              hipStream_t stream) {
    (void)in_sizes; (void)n_in; (void)out_size;
    const float* spec_re = (const float*)d_in[0];
    const float* spec_im = (const float*)d_in[1];
    const float* mask    = (const float*)d_in[2];
    float* out = (float*)d_out;
    const int nstrip = 16*127*768;
    const size_t ws_need = 2ull * 16 * 128 * 768 * 4;   // 12.6 MB
    if (ws_size >= ws_need && d_ws != nullptr) {
        float* wsL = (float*)d_ws;
        float* wsR = wsL + 16ull*128*768;
        istft_main<true><<<dim3(128, 16), 512, 0, stream>>>(spec_re, spec_im, mask, out, wsL, wsR);
        istft_fixup_ws<<<(nstrip + 255)/256, 256, 0, stream>>>(wsL, wsR, out);
    } else {
        istft_zero<<<(nstrip + 255)/256, 256, 0, stream>>>(out);
        istft_main<false><<<dim3(128, 16), 512, 0, stream>>>(spec_re, spec_im, mask, out, nullptr, nullptr);
        istft_fixup_at<<<(nstrip + 255)/256, 256, 0, stream>>>(out);
    }
}

// Round 10
// 77.437 us; speedup vs baseline: 1.4453x; 1.4100x over previous
//
#include <hip/hip_runtime.h>

#define THREADS 512

// raw barrier: wait LDS ops only (NOT vmcnt) so global loads/stores stay in
// flight across the barrier. "memory" clobber pins C++ LDS access order.
#define BAR() do { asm volatile("s_waitcnt lgkmcnt(0)" ::: "memory"); \
                   __builtin_amdgcn_s_barrier();                      \
                   asm volatile("" ::: "memory"); } while (0)

// read one real sample j (0..1023) of frame-slot F (0..15) from split re/im slots
#define SLOTRD(F, j) s_slot[((j) & 1)*8352 + (F)*522 + ((j) >> 1)]

// -------- radix-8 inverse DFT over register index: u[n] = sum_k v[k] e^{+2*pi*i*n*k/8}
__device__ __forceinline__ void dft8(float* vr, float* vi) {
    float t0r=vr[0]+vr[4], t0i=vi[0]+vi[4];
    float t1r=vr[0]-vr[4], t1i=vi[0]-vi[4];
    float t2r=vr[2]+vr[6], t2i=vi[2]+vi[6];
    float t3r=vr[2]-vr[6], t3i=vi[2]-vi[6];
    float t4r=vr[1]+vr[5], t4i=vi[1]+vi[5];
    float t5r=vr[1]-vr[5], t5i=vi[1]-vi[5];
    float t6r=vr[3]+vr[7], t6i=vi[3]+vi[7];
    float t7r=vr[3]-vr[7], t7i=vi[3]-vi[7];
    float e0r=t0r+t2r, e0i=t0i+t2i;
    float e1r=t1r-t3i, e1i=t1i+t3r;   // t1 + i*t3
    float e2r=t0r-t2r, e2i=t0i-t2i;
    float e3r=t1r+t3i, e3i=t1i-t3r;   // t1 - i*t3
    float o0r=t4r+t6r, o0i=t4i+t6i;
    float o1r=t5r-t7i, o1i=t5i+t7r;
    float o2r=t4r-t6r, o2i=t4i-t6i;
    float o3r=t5r+t7i, o3i=t5i-t7r;
    const float C = 0.70710678118654752f;
    float w1r = C*(o1r - o1i), w1i = C*(o1r + o1i);   // W8^1 * o1
    float w2r = -o2i,          w2i = o2r;             // i * o2
    float w3r = -C*(o3r + o3i), w3i = C*(o3r - o3i);  // W8^3 * o3
    vr[0]=e0r+o0r; vi[0]=e0i+o0i;
    vr[1]=e1r+w1r; vi[1]=e1i+w1i;
    vr[2]=e2r+w2r; vi[2]=e2i+w2i;
    vr[3]=e3r+w3r; vi[3]=e3i+w3i;
    vr[4]=e0r-o0r; vi[4]=e0i-o0i;
    vr[5]=e1r-w1r; vi[5]=e1i-w1i;
    vr[6]=e2r-w2r; vi[6]=e2i-w2i;
    vr[7]=e3r-w3r; vi[7]=e3i-w3i;
}

// packed irfft-1024 as 512-pt complex IFFT, in-place in split re/im slot
__device__ __forceinline__ void fft512(float* Re, float* Im, int l,
                                       const float2* s_twzb, const float2* s_tw64,
                                       const float2* s_tw512) {
    const int a_ = l >> 3, b_ = l & 7;
    float zr[8], zi[8];
    float cw = s_twzb[l].x, sw_ = s_twzb[l].y;
    const float C8 = 0.92387953251128675f, S8 = 0.38268343236508977f; // e^{i*pi/8}
    #pragma unroll
    for (int k0 = 0; k0 < 8; ++k0) {
        int k = (k0<<6) + l;
        float xkr = Re[k],     xki = Im[k];
        float xmr = Re[512-k], xmi = Im[512-k];
        if (k == 0) { xki = 0.f; xmi = 0.f; }   // zero Im(X0), Im(X512)
        float Er = 0.5f*(xkr + xmr), Ei = 0.5f*(xki - xmi);
        float Dr = 0.5f*(xkr - xmr), Di = 0.5f*(xki + xmi);
        float Or = cw*Dr - sw_*Di,  Oi = sw_*Dr + cw*Di;
        zr[k0] = Er - Oi;
        zi[k0] = Ei + Or;
        float nc = cw*C8 - sw_*S8; sw_ = sw_*C8 + cw*S8; cw = nc;
    }
    dft8(zr, zi);
    // exchange 1 (XOR-swizzled, <=2-way)
    #pragma unroll
    for (int q = 0; q < 8; ++q) {
        int idx = (q<<6) + l;
        Re[idx ^ (((idx>>6)&7)<<3)] = zr[q];
        Im[idx ^ (((idx>>6)&7)<<3)] = zi[q];
    }
    #pragma unroll
    for (int q = 0; q < 8; ++q) {
        int idx = (a_<<6) + (q<<3) + b_;
        int ph = idx ^ (((idx>>6)&7)<<3);
        zr[q] = Re[ph]; zi[q] = Im[ph];
    }
    { // twiddle2: w64^{n0*k1}, incremental
        float c1 = s_tw64[a_].x, s1 = s_tw64[a_].y;
        float cr = c1, ci = s1;
        #pragma unroll
        for (int q = 1; q < 8; ++q) {
            float tr = zr[q]*cr - zi[q]*ci;
            zi[q] = zr[q]*ci + zi[q]*cr;
            zr[q] = tr;
            float nc = cr*c1 - ci*s1; ci = ci*c1 + cr*s1; cr = nc;
        }
    }
    dft8(zr, zi);
    // exchange 2
    #pragma unroll
    for (int q = 0; q < 8; ++q) {
        int idx = (b_<<6) + (q<<3) + a_;
        int ph = idx ^ (((idx>>6)&7)<<3);
        Re[ph] = zr[q]; Im[ph] = zi[q];
    }
    #pragma unroll
    for (int q = 0; q < 8; ++q) {
        int idx = (q<<6) + l;
        int ph = idx ^ (((idx>>6)&7)<<3);
        zr[q] = Re[ph]; zi[q] = Im[ph];
    }
    { // twiddle3: w512^{(n1*8+n0)*k2}, incremental
        float c1 = s_tw512[l].x, s1 = s_tw512[l].y;
        float cr = c1, ci = s1;
        #pragma unroll
        for (int q = 1; q < 8; ++q) {
            float tr = zr[q]*cr - zi[q]*ci;
            zi[q] = zr[q]*ci + zi[q]*cr;
            zr[q] = tr;
            float nc = cr*c1 - ci*s1; ci = ci*c1 + cr*s1; cr = nc;
        }
    }
    dft8(zr, zi);
    // output: lane l, reg q holds z[64q + l]; x[2n]=Re z[n], x[2n+1]=Im z[n]
    #pragma unroll
    for (int q = 0; q < 8; ++q) {
        Re[(q<<6) + l] = zr[q];
        Im[(q<<6) + l] = zi[q];
    }
}

// one block = (batch b, 16 frames), 16 LDS slots, SINGLE stage/FFT/gather phase.
// All 64B of each spectrum row are read by 4 consecutive lanes in one coalesced
// instruction -> read-once from HBM by construction (R9 lesson: temporal split
// of a line gets evicted; spatial split within one phase does not).
template<bool USE_WS>
__global__ __launch_bounds__(512, 4) void istft_main(const float* __restrict__ spec_re,
                                                     const float* __restrict__ spec_im,
                                                     const float* __restrict__ mask,
                                                     float* __restrict__ out,
                                                     float* __restrict__ wsL,
                                                     float* __restrict__ wsR)
{
    const int G   = blockIdx.x;   // frame-group 0..127 (frames [16G, 16G+16))
    const int b   = blockIdx.y;   // batch 0..15
    const int tid = threadIdx.x;

    __shared__ float  s_slot[16704];  // 16 slots x 522: re [0,8352), im [8352,16704)
    __shared__ float  s_wt[1024];     // hann(j)/512
    __shared__ float  s_envr[256];    // 1 / (periodic fold of hann^2)
    __shared__ float  s_maskx[22];    // mask frames 16G-3 .. 16G+18 (OOR = 0)
    __shared__ float  s_ps[23];       // prefix sums of s_maskx
    __shared__ float2 s_twzb[64];     // e^{i*pi*l/512}
    __shared__ float2 s_tw64[8];      // e^{2*pi*i*a/64}
    __shared__ float2 s_tw512[64];    // e^{2*pi*i*l/512}

    // ---- issue ALL global loads FIRST (latency hides under table build) ----
    // chunk c = tid&3 (frames 4c..4c+3); rows r0+128k, k=0..3. Lanes tid..tid+3
    // cover one full 64B row line -> perfectly coalesced, read-once.
    const size_t base = (size_t)b * 513 * 2048 + (size_t)(G * 16);
    const int c  = tid & 3;
    const int r0 = tid >> 2;
    float4 vr0, vi0, vr1, vi1, vr2, vi2, vr3, vi3, nyr, nyi;
    float4 mk;
    float mxv = 0.f;
    {
        size_t o0 = base + (size_t)(r0      ) * 2048 + (size_t)(c * 4);
        size_t o1 = base + (size_t)(r0 + 128) * 2048 + (size_t)(c * 4);
        size_t o2 = base + (size_t)(r0 + 256) * 2048 + (size_t)(c * 4);
        size_t o3 = base + (size_t)(r0 + 384) * 2048 + (size_t)(c * 4);
        vr0 = *(const float4*)(spec_re + o0);  vi0 = *(const float4*)(spec_im + o0);
        vr1 = *(const float4*)(spec_re + o1);  vi1 = *(const float4*)(spec_im + o1);
        vr2 = *(const float4*)(spec_re + o2);  vi2 = *(const float4*)(spec_im + o2);
        vr3 = *(const float4*)(spec_re + o3);  vi3 = *(const float4*)(spec_im + o3);
        if (tid < 4) {   // Nyquist row 512, chunk tid (== c)
            size_t o4 = base + (size_t)512 * 2048 + (size_t)(tid * 4);
            nyr = *(const float4*)(spec_re + o4);
            nyi = *(const float4*)(spec_im + o4);
        }
        mk = *(const float4*)(mask + b*2048 + G*16 + c*4);
        if (tid < 22) {
            int gf = G*16 - 3 + tid;
            mxv = (gf >= 0 && gf < 2048) ? mask[b*2048 + gf] : 0.f;
        }
    }

    // ---- tables (hardware trig; accuracy ~1e-5 << 2e-2 threshold) ----
    for (int i = tid; i < 1024; i += THREADS) {
        float w = 0.5f - 0.5f * __cosf(6.2831853071795864f * (float)i * (1.0f/1024.0f));
        s_wt[i] = w * (1.0f/512.0f);
    }
    if (tid < 256) {
        float e = 0.f;
        #pragma unroll
        for (int k = 0; k < 4; ++k) {
            float w = 0.5f - 0.5f * __cosf(6.2831853071795864f * (float)(tid + (k<<8)) * (1.0f/1024.0f));
            e += w * w;
        }
        s_envr[tid] = 1.0f / e;
    }
    if (tid < 64) {
        float s1, c1, s2, c2;
        __sincosf(3.1415926535897932f * (float)tid * (1.0f/512.0f), &s1, &c1);
        s_twzb[tid] = make_float2(c1, s1);
        __sincosf(6.2831853071795864f * (float)tid * (1.0f/512.0f), &s2, &c2);
        s_tw512[tid] = make_float2(c2, s2);
    }
    if (tid < 8) {
        float s3, c3;
        __sincosf(6.2831853071795864f * (float)tid * (1.0f/64.0f), &s3, &c3);
        s_tw64[tid] = make_float2(c3, s3);
    }
    if (tid < 22) s_maskx[tid] = mxv;

    // ---- stage all 16 frames, mask folded ----
    {
        const float* mp = (const float*)&mk;
        #pragma unroll
        for (int f = 0; f < 4; ++f) {
            int fr = (c*4 + f) * 522;
            s_slot[       fr + r0      ] = ((const float*)&vr0)[f] * mp[f];
            s_slot[8352 + fr + r0      ] = ((const float*)&vi0)[f] * mp[f];
            s_slot[       fr + r0 + 128] = ((const float*)&vr1)[f] * mp[f];
            s_slot[8352 + fr + r0 + 128] = ((const float*)&vi1)[f] * mp[f];
            s_slot[       fr + r0 + 256] = ((const float*)&vr2)[f] * mp[f];
            s_slot[8352 + fr + r0 + 256] = ((const float*)&vi2)[f] * mp[f];
            s_slot[       fr + r0 + 384] = ((const float*)&vr3)[f] * mp[f];
            s_slot[8352 + fr + r0 + 384] = ((const float*)&vi3)[f] * mp[f];
        }
        if (tid < 4) {
            #pragma unroll
            for (int f = 0; f < 4; ++f) {
                int fr = (tid*4 + f) * 522;
                s_slot[       fr + 512] = ((const float*)&nyr)[f] * mp[f];
                s_slot[8352 + fr + 512] = ((const float*)&nyi)[f] * mp[f];
            }
        }
    }
    if (tid == 0) {
        float acc = 0.f;
        s_ps[0] = 0.f;
        #pragma unroll
        for (int i = 0; i < 22; ++i) { acc += s_maskx[i]; s_ps[i+1] = acc; }
    }
    BAR();   // staging + tables visible

    // ---- FFT: wave wv handles frames wv and wv+8 (two independent FFTs, 2x ILP) ----
    __builtin_amdgcn_s_setprio(1);
    {
        const int wv = tid >> 6, l = tid & 63;
        fft512(&s_slot[wv*522],     &s_slot[8352 + wv*522],     l, s_twzb, s_tw64, s_tw512);
        fft512(&s_slot[(wv+8)*522], &s_slot[8352 + (wv+8)*522], l, s_twzb, s_tw64, s_tw512);
    }
    __builtin_amdgcn_s_setprio(0);
    BAR();   // FFT results visible

    // ---- gather + retire: p = v*512 + tid, p < 4864 ----
    const int P0 = G << 12;   // 4096*G
    float* yout = out + (size_t)b * 524288;
    float* mout = out + 16ull*524288 + (size_t)b * 524288;

    // left strip p in [0,768)
    #pragma unroll
    for (int v = 0; v < 2; ++v) {
        int p = (v << 9) + tid;
        if (v == 0 || tid < 256) {
            int thi = p >> 8;                 // 0..2
            float acc = 0.f;
            for (int F = 0; F <= thi; ++F) {
                int j = p - (F << 8);
                acc += SLOTRD(F, j) * s_wt[j];
            }
            float fm = s_ps[thi + 4] - s_ps[((p - 768) >> 8) + 3];
            if (G == 0) {
                if (p >= 384) {
                    float e = 0.f;
                    for (int t = 0; t <= thi; ++t) {
                        float w = s_wt[p - (t << 8)] * 512.0f;
                        e += w * w;
                    }
                    yout[p - 384] = acc / e;
                    mout[p - 384] = (fm > 0.f) ? 1.0f : 0.0f;
                }
            } else {
                int s = P0 + p - 384;
                if (USE_WS) wsL[(size_t)((b << 7) + G) * 768 + p] = acc;
                else        atomicAdd(&yout[s], acc);
                mout[s] = (fm > 0.f) ? 1.0f : 0.0f;
            }
        }
    }
    // interior p in [768,4096): exactly 4 terms, periodic env
    #pragma unroll
    for (int v = 1; v < 8; ++v) {
        int p = (v << 9) + tid;
        if (v > 1 || tid >= 256) {
            int F0 = (p >> 8) - 3;             // 0..12
            float acc = 0.f;
            #pragma unroll
            for (int u = 0; u < 4; ++u) {
                int F = F0 + u;
                int j = p - (F << 8);
                acc += SLOTRD(F, j) * s_wt[j];
            }
            float fm = s_ps[(p >> 8) + 4] - s_ps[F0 + 3];
            int s = P0 + p - 384;
            yout[s] = acc * s_envr[p & 255];
            mout[s] = (fm > 0.f) ? 1.0f : 0.0f;
        }
    }
    // right strip p in [4096,4864)
    #pragma unroll
    for (int v = 0; v < 2; ++v) {
        int p = 4096 + (v << 9) + tid;
        if (v == 0 || tid < 256) {
            int Flo = (p - 768) >> 8;          // 13..15
            float acc = 0.f;
            for (int F = Flo; F < 16; ++F) {
                int j = p - (F << 8);
                acc += SLOTRD(F, j) * s_wt[j];
            }
            float fm = s_ps[min(p >> 8, 18) + 4] - s_ps[Flo + 3];
            if (G == 127) {
                if (p < 4480) {
                    float e = 0.f;
                    for (int t = Flo; t < 16; ++t) {
                        float w = s_wt[p - (t << 8)] * 512.0f;
                        e += w * w;
                    }
                    int s = P0 + p - 384;
                    yout[s] = acc / e;
                    mout[s] = (fm > 0.f) ? 1.0f : 0.0f;
                }
            } else {
                int s = P0 + p - 384;
                if (USE_WS) wsR[(size_t)((b << 7) + G) * 768 + (p - 4096)] = acc;
                else        atomicAdd(&yout[s], acc);
                mout[s] = (fm > 0.f) ? 1.0f : 0.0f;
            }
        }
    }
}

// ws path: combine the two strip partials, divide by (periodic) env.
__global__ void istft_fixup_ws(const float* __restrict__ wsL, const float* __restrict__ wsR,
                               float* __restrict__ out) {
    int idx = blockIdx.x * 256 + threadIdx.x;
    if (idx >= 16*127*768) return;
    int q  = idx % 768;
    int t_ = idx / 768;
    int g  = (t_ % 127) + 1;
    int b  = t_ / 127;
    float a = wsR[(size_t)((b << 7) + (g-1)) * 768 + q]
            + wsL[(size_t)((b << 7) + g) * 768 + q];
    int j0 = q & 255;
    float e = 0.f;
    #pragma unroll
    for (int u = 0; u < 4; ++u) {
        float w = 0.5f - 0.5f * __cosf(6.2831853071795864f * (float)(j0 + (u<<8)) * (1.0f/1024.0f));
        e += w * w;
    }
    out[(size_t)b*524288 + (size_t)((g << 12) + q - 384)] = a / e;
}

// atomic-fallback path
__global__ void istft_zero(float* __restrict__ out) {
    int idx = blockIdx.x * 256 + threadIdx.x;
    if (idx >= 16*127*768) return;
    int q  = idx % 768;
    int t_ = idx / 768;
    int g  = (t_ % 127) + 1;
    int b  = t_ / 127;
    out[(size_t)b*524288 + (g << 12) + q - 384] = 0.f;
}

__global__ void istft_fixup_at(float* __restrict__ out) {
    int idx = blockIdx.x * 256 + threadIdx.x;
    if (idx >= 16*127*768) return;
    int q  = idx % 768;
    int t_ = idx / 768;
    int g  = (t_ % 127) + 1;
    int b  = t_ / 127;
    int j0 = q & 255;
    float e = 0.f;
    #pragma unroll
    for (int u = 0; u < 4; ++u) {
        float w = 0.5f - 0.5f * __cosf(6.2831853071795864f * (float)(j0 + (u<<8)) * (1.0f/1024.0f));
        e += w * w;
    }
    size_t o = (size_t)b*524288 + (size_t)((g << 12) + q - 384);
    out[o] = out[o] / e;
}

extern "C" void kernel_launch(void* const* d_in, const int* in_sizes, int n_in,
                              void* d_out, int out_size, void* d_ws, size_t ws_size,
                              hipStream_t stream) {
    (void)in_sizes; (void)n_in; (void)out_size;
    const float* spec_re = (const float*)d_in[0];
    const float* spec_im = (const float*)d_in[1];
    const float* mask    = (const float*)d_in[2];
    float* out = (float*)d_out;
    const int nstrip = 16*127*768;
    const size_t ws_need = 2ull * 16 * 128 * 768 * 4;   // 12.6 MB
    if (ws_size >= ws_need && d_ws != nullptr) {
        float* wsL = (float*)d_ws;
        float* wsR = wsL + 16ull*128*768;
        istft_main<true><<<dim3(128, 16), 512, 0, stream>>>(spec_re, spec_im, mask, out, wsL, wsR);
        istft_fixup_ws<<<(nstrip + 255)/256, 256, 0, stream>>>(wsL, wsR, out);
    } else {
        istft_zero<<<(nstrip + 255)/256, 256, 0, stream>>>(out);
        istft_main<false><<<dim3(128, 16), 512, 0, stream>>>(spec_re, spec_im, mask, out, nullptr, nullptr);
        istft_fixup_at<<<(nstrip + 255)/256, 256, 0, stream>>>(out);
    }
}